// Round 12
// baseline (233.993 us; speedup 1.0000x reference)
//
#include <hip/hip_runtime.h>
#include <stdint.h>

// PoolingNms: 3 chained pool/unpool passes (k=3,5,6) on 16x1x1080x1920 fp32.
// lcm(3,5,6)=30 -> every 30x30 tile independent; 30x240 strips keep global
// accesses 64B-line-aligned (R1: else WRITE_SIZE amplifies).
//
// R11 post-mortem: full-strip load MLP via global_load_lds achieved (traffic
// byte-exact) and dur STAYED 88us -> compute phase is the cost. Shuffle
// formulation = 180 ds_bpermute/wave, serialized by the compiler's 28-VGPR
// schedule -> ~21us/wave of raw DS latency. The algorithm, not the memory
// path, is DS-latency-bound. Irreducible (~2K bpermutes/window/lane).
//
// R12: banded compute (R4's structure, hardware-validated absmax=0) at 2x
// the occupancy. Thread = (row r, 30-col band b): horizontal K-max local;
// vertical K-max via INDEPENDENT b128 reads of a compact hmax buffer.
// ~76 DS ops/thread, short chains. R4 ran 100us at 2 blocks/CU (60.5KB);
// here LDS = 40.8KB -> 4 blocks/CU = 16 waves:
//  - single hbuf (30 x 96 floats; band offsets 12 floats, b128-aligned,
//    per-band bank-quads distinct) instead of R4's 2x132-stride regions
//  - tile row stride 244 floats (breaks the stride-240 bank pattern behind
//    R4's 6.1M conflicts; per-row global_load_lds dest stays linear)
//  - global_load_lds staging (R11-proven); no prefetch pipeline - overlap
//    comes from 4 resident blocks. 7 __syncthreads per strip.
// Tie semantics (== jnp.argmax row-major first-occurrence), proven in R4:
// vertical ascending strict-'>' scan of row-hmaxes -> first row; in-row
// seen-flag scan -> first col. Exact fp compares, no value arithmetic.

#define IMG_H 1080
#define IMG_W 1920
#define TH 30
#define TW 240
#define TS 244            // tile row stride (floats): bank-spread, 16B-aligned
#define HS 96             // hbuf row stride (floats)
#define HB 12             // hbuf floats per band (max NG*4 = 12, K=3)
#define NTHREADS 256

#define GPTR(p) ((const __attribute__((address_space(1))) void*)(p))
#define LPTR(p) ((__attribute__((address_space(3))) void*)(p))

// One stage over register-resident band v[30] (row r, cols [30b, 30b+30)).
// hbuf: 30 x HS compact row-hmax exchange. One barrier inside (hwrite ->
// vread); caller provides the barrier between stages (vread -> next hwrite).
template <int K>
__device__ __forceinline__ void stage(float (&v)[30], float* __restrict__ hbuf,
                                      int r, int b, bool act) {
    constexpr int NH = 30 / K;        // windows along the 30-col band
    constexpr int NG = (NH + 3) / 4;  // 16B granules exchanged
    if (act) {
        float hp[NG * 4];
#pragma unroll
        for (int q = 0; q < NG * 4; ++q) hp[q] = 0.0f;
#pragma unroll
        for (int j = 0; j < NH; ++j) {   // horizontal K-max, thread-local
            float m = v[j * K];
#pragma unroll
            for (int c = 1; c < K; ++c) m = fmaxf(m, v[j * K + c]);
            hp[j] = m;
        }
        float* w = hbuf + r * HS + b * HB;
#pragma unroll
        for (int q = 0; q < NG; ++q)
            *reinterpret_cast<float4*>(w + 4 * q) =
                *reinterpret_cast<const float4*>(&hp[4 * q]);
    }
    __syncthreads();
    if (act) {
        const int g = r / K;          // window row-group
        const int myrr = r - g * K;   // my row within the group
        float best[NH];
        int frow[NH];
#pragma unroll
        for (int j = 0; j < NH; ++j) { best[j] = -1.0f; frow[j] = -1; }
        const float* vb = hbuf + (g * K) * HS + b * HB;
        // K*NG independent b128 reads; ascending + strict '>' keeps the
        // FIRST row achieving each window max.
#pragma unroll
        for (int rr = 0; rr < K; ++rr) {
            float hr[NG * 4];
#pragma unroll
            for (int q = 0; q < NG; ++q)
                *reinterpret_cast<float4*>(&hr[4 * q]) =
                    *reinterpret_cast<const float4*>(vb + rr * HS + 4 * q);
#pragma unroll
            for (int j = 0; j < NH; ++j)
                if (hr[j] > best[j]) { best[j] = hr[j]; frow[j] = rr; }
        }
        // keep only the first (row-major) occurrence of the max
#pragma unroll
        for (int j = 0; j < NH; ++j) {
            const bool rowwin = (frow[j] == myrr);
            bool seen = false;
#pragma unroll
            for (int c = 0; c < K; ++c) {
                const int idx = j * K + c;
                const bool eq = (v[idx] == best[j]);
                if (!(rowwin && eq && !seen)) v[idx] = 0.0f;
                seen = seen || eq;
            }
        }
    }
}

__global__ __launch_bounds__(NTHREADS) void pooling_nms_kernel(
    const float* __restrict__ x, float* __restrict__ out) {
    __shared__ float tile[TH * TS];   // 29280 B
    __shared__ float hbuf[TH * HS];   // 11520 B  -> total 40800 B, 4 blk/CU

    const int t = threadIdx.x;
    const int w = t >> 6;             // wave 0..3
    const int lane = t & 63;

    const size_t base = (size_t)blockIdx.z * (IMG_H * (size_t)IMG_W) +
                        (size_t)(blockIdx.y * TH) * IMG_W + blockIdx.x * TW;
    const float* src = x + base;
    float* dst = out + base;

    // ---- Load: one register-free global_load_lds dwordx4 per row
    // (60 lanes x 16B = 960B row); rows round-robin over waves -> whole
    // strip (28.8 KB payload) in flight at once. Dest linear per row.
    if (lane < 60) {
        for (int r = w; r < TH; r += 4)
            __builtin_amdgcn_global_load_lds(
                GPTR(src + (size_t)r * IMG_W + lane * 4),
                LPTR(&tile[r * TS + lane * 4]), 16, 0, 0);
    }
    __syncthreads();

    // ---- Compute: thread = (row r, band b). 240 active threads.
    const int r = t >> 3;             // 0..31 (30,31 idle)
    const int b = t & 7;              // band 0..7
    const bool act = r < TH;

    float v[30];
    if (act) {
        const float* tp = &tile[r * TS + b * 30];
#pragma unroll
        for (int k = 0; k < 15; ++k)  // 8B-aligned b64 reads
            *reinterpret_cast<float2*>(&v[2 * k]) =
                *reinterpret_cast<const float2*>(&tp[2 * k]);
    }

    stage<3>(v, hbuf, r, b, act);
    __syncthreads();                  // vread done -> hbuf reusable
    stage<5>(v, hbuf, r, b, act);
    __syncthreads();
    stage<6>(v, hbuf, r, b, act);

    if (act) {                        // writeback band -> tile
        float* tp = &tile[r * TS + b * 30];
#pragma unroll
        for (int k = 0; k < 15; ++k)
            *reinterpret_cast<float2*>(&tp[2 * k]) =
                *reinterpret_cast<const float2*>(&v[2 * k]);
    }
    __syncthreads();                  // results visible

    // ---- Store: coalesced b128; 960B rows line-aligned, partial lines
    // never cross blocks -> no write amplification.
    if (lane < 60) {
        for (int rr = w; rr < TH; rr += 4) {
            const float4 val =
                *reinterpret_cast<const float4*>(&tile[rr * TS + lane * 4]);
            *reinterpret_cast<float4*>(dst + (size_t)rr * IMG_W + lane * 4) = val;
        }
    }
}

extern "C" void kernel_launch(void* const* d_in, const int* in_sizes, int n_in,
                              void* d_out, int out_size, void* d_ws, size_t ws_size,
                              hipStream_t stream) {
    const float* x = (const float*)d_in[0];
    float* out = (float*)d_out;
    dim3 grid(IMG_W / TW, IMG_H / TH, 16);  // 8 x 36 x 16 = 4608 blocks
    pooling_nms_kernel<<<grid, NTHREADS, 0, stream>>>(x, out);
}